// Round 11
// baseline (196.846 us; speedup 1.0000x reference)
//
#include <hip/hip_runtime.h>

typedef __bf16 bf16;
typedef __bf16 bf16x8 __attribute__((ext_vector_type(8)));
typedef float f32x4 __attribute__((ext_vector_type(4)));

#define M_TOT 4096
#define D_IN  784
#define HALF  392
#define MID   1000
#define K0PAD 448   // 392 -> mult of 64
#define NPAD  1024  // 1000 padded

// ---------- async global->LDS 16B ----------
__device__ __forceinline__ void g2l16(const bf16* g, bf16* l) {
  __builtin_amdgcn_global_load_lds(
      (__attribute__((address_space(1))) void*)(g),
      (__attribute__((address_space(3))) void*)(l),
      16, 0, 0);
}

// ---------- 32x32 weight-transpose tile: W (KxN f32) -> WT (Npad x Kpad bf16) ----------
__device__ __forceinline__ void wtrans_tile(const float* __restrict__ W, bf16* __restrict__ WT,
                                            int K, int N, int Kpad, int tn, int tk,
                                            float (*tb)[33], int tid) {
  int n0 = tn * 32, k0 = tk * 32;
  int tx = tid & 31, ty = tid >> 5;
#pragma unroll
  for (int r = 0; r < 4; ++r) {
    int k = k0 + ty + 8 * r, n = n0 + tx;
    tb[ty + 8 * r][tx] = (k < K && n < N) ? W[(size_t)k * N + n] : 0.f;
  }
  __syncthreads();
#pragma unroll
  for (int r = 0; r < 4; ++r) {
    int n = n0 + ty + 8 * r, k = k0 + tx;
    WT[(size_t)n * Kpad + k] = (bf16)tb[tx][ty + 8 * r];
  }
}

// ---------- prep: pack x-even (vectorized), ALL weight transposes, ldj ----------
// grid: 896 pack blocks + 5056 transpose blocks = 5952 (R9-verified)
__global__ void prep_k(const float* __restrict__ x, const float* __restrict__ ldj,
                       const float* __restrict__ W_in, const float* __restrict__ W_hid,
                       const float* __restrict__ W_out,
                       bf16* __restrict__ A0, bf16* __restrict__ WT0,
                       bf16* __restrict__ WTh, bf16* __restrict__ WT5,
                       float* __restrict__ y) {
  __shared__ float tb[32][33];
  const int b = blockIdx.x, tid = threadIdx.x;
  if (b < 896) {  // pack: each thread produces 8 consecutive k of one row
    int g = b * 256 + tid;          // 0 .. 229375
    int m = g / 56;                 // 56 groups of 8 cover K0PAD=448
    int kq = g - m * 56, k0 = kq * 8;
    bf16x8 v;
    if (k0 < HALF) {                // kq<=48 -> k0<=384, all 8 k valid (<392)
      const float4* xr = (const float4*)(x + (size_t)m * D_IN + 2 * k0);
      float4 a0 = xr[0], a1 = xr[1], a2 = xr[2], a3 = xr[3];
      v[0] = (bf16)a0.x; v[1] = (bf16)a0.z;
      v[2] = (bf16)a1.x; v[3] = (bf16)a1.z;
      v[4] = (bf16)a2.x; v[5] = (bf16)a2.z;
      v[6] = (bf16)a3.x; v[7] = (bf16)a3.z;
    } else {
#pragma unroll
      for (int j = 0; j < 8; ++j) v[j] = (bf16)0.f;
    }
    *(bf16x8*)(A0 + (size_t)m * K0PAD + k0) = v;
    if (b == 0 && tid == 0) y[(size_t)M_TOT * D_IN] = ldj[0];
    return;
  }
  int t = b - 896;
  const float* W; bf16* WT; int K, N, Kpad, tn, tk;
  if (t < 448) {                 // W_in: (392 x 1000) -> (1024 x 448)
    W = W_in; WT = WT0; K = HALF; N = MID; Kpad = K0PAD;
    tn = t & 31; tk = t >> 5;
  } else if (t < 4544) {         // W_hid[i]: (1000 x 1000) -> (1024 x 1024)
    int u = t - 448; int i = u >> 10; u &= 1023;
    W = W_hid + (size_t)i * MID * MID; WT = WTh + (size_t)i * NPAD * NPAD;
    K = MID; N = MID; Kpad = NPAD;
    tn = u & 31; tk = u >> 5;
  } else {                       // W_out: (1000 x 392) -> (512 x 1024)
    int u = t - 4544;
    W = W_out; WT = WT5; K = MID; N = HALF; Kpad = NPAD;
    tn = u & 15; tk = u >> 4;
  }
  wtrans_tile(W, WT, K, N, Kpad, tn, tk, tb, tid);
}

// ---------- GEMM: BM x BN tile, BK=64, 4 waves (64x64/wave at BN=128), ----------
// ---------- 3-buffer LDS, counted vmcnt, COMPILER-SCHEDULED frag reads ----------
// Per-wave 64x64 sub-tile = 512 B LDS-read per MFMA -> LDS-BW cap ~31% MfmaUtil
// (vs 21% for 64x32, 16% for 32x32 — matches all measured configs). Frag reads and
// MFMAs are intentionally UNPINNED (no sched_barrier/lgkmcnt between them): the
// compiler interleaves them with partial lgkmcnt(N) waits (m97 asm evidence);
// pinning them (R9) serialized 24 reads before any MFMA. lgkmcnt(0) appears only
// before the buffer-release barrier. Staging depth 2-ahead via NBUF=3 + counted vmcnt.
// EPI=0: C = relu(acc + bias) bf16, stride NPAD.
// EPI=1: y pairs: y[m][2n]=x[m][2n]; y[m][2n+1]=x[m][2n+1]+acc+bias[n] (n<HALF)
template <int BM, int BN, int EPI, int K>
__global__ __launch_bounds__(256)
void gemm_k(const bf16* __restrict__ A, const bf16* __restrict__ BT,
            const float* __restrict__ bias, int bias_n,
            bf16* __restrict__ C,
            const float* __restrict__ x, float* __restrict__ y) {
  constexpr int BK = 64, NBUF = 3;
  constexpr int MT = BM / 32, NT = BN / 32;
  constexpr int KT = K / BK;
  constexpr int NBM = M_TOT / BM;             // 32
  constexpr int AI = (BM / 4) / 8;            // A g2l16 per wave per stage
  constexpr int BI = (BN / 4) / 8;            // B g2l16 per wave per stage
  constexpr int LPS = AI + BI;
  static_assert(K % BK == 0 && KT >= NBUF, "K/BK");

  alignas(16) __shared__ bf16 ldsA[NBUF][BM * BK];
  alignas(16) __shared__ bf16 ldsB[NBUF][BN * BK];
  const int tid = threadIdx.x;
  const int id = blockIdx.x;

  const int wave = tid >> 6, lane = tid & 63;
  const int bm = id % NBM, bn = id / NBM;

  // staging: 8 lanes/row, global 16B-chunk XOR-swizzled by row%8, linear LDS dest
  const int srow = lane >> 3;
  const int scol = lane & 7;
  const bf16* gAb = A + ((size_t)bm * BM + wave * (BM / 4)) * K;
  const bf16* gBb = BT + ((size_t)bn * BN + wave * (BN / 4)) * K;
  const int lAo = wave * (BM / 4) * BK;
  const int lBo = wave * (BN / 4) * BK;

  // fragment geometry (R4-verified for BN=128, R5-verified for BN=64)
  const int mlane = lane & 15, quad = lane >> 4;
  const int wm = (wave & 1) * (BM / 2), wn = (wave >> 1) * (BN / 2);
  const int axor = mlane & 7;

  auto stage = [&](int kt, int pb) {
    const int koff = kt * BK;
#pragma unroll
    for (int i = 0; i < AI; ++i) {
      int r = i * 8 + srow;
      g2l16(gAb + (size_t)r * K + koff + (scol ^ (r & 7)) * 8,
            &ldsA[pb][lAo + i * 8 * BK]);
    }
#pragma unroll
    for (int i = 0; i < BI; ++i) {
      int r = i * 8 + srow;
      g2l16(gBb + (size_t)r * K + koff + (scol ^ (r & 7)) * 8,
            &ldsB[pb][lBo + i * 8 * BK]);
    }
  };

  f32x4 acc[MT][NT] = {};

  stage(0, 0); stage(1, 1); stage(2, 2);

  int pb = 0;
  for (int kt = 0; kt < KT; ++kt) {
    const int rem = KT - 1 - kt;   // future tiles still in flight beyond kt
    if (rem >= 2)
      asm volatile("s_waitcnt vmcnt(%0)" ::"n"(2 * LPS) : "memory");
    else if (rem == 1)
      asm volatile("s_waitcnt vmcnt(%0)" ::"n"(LPS) : "memory");
    else
      asm volatile("s_waitcnt vmcnt(0)" ::: "memory");
    __builtin_amdgcn_s_barrier();            // tile kt staging landed (all waves)
    __builtin_amdgcn_sched_barrier(0);       // no reads hoisted above barrier

    // ---- frag reads + MFMA: UNPINNED (compiler interleaves with partial lgkmcnt) ----
    const bf16* raB = &ldsA[pb][(wm + mlane) * BK];
    const bf16* rbB = &ldsB[pb][(wn + mlane) * BK];
    bf16x8 af[2][MT], bfr[2][NT];
#pragma unroll
    for (int s = 0; s < 2; ++s) {
      const int co = ((s * 4 + quad) ^ axor) * 8;
#pragma unroll
      for (int i = 0; i < MT; ++i) af[s][i] = *(const bf16x8*)(raB + i * 16 * BK + co);
#pragma unroll
      for (int i = 0; i < NT; ++i) bfr[s][i] = *(const bf16x8*)(rbB + i * 16 * BK + co);
    }
#pragma unroll
    for (int s = 0; s < 2; ++s)
#pragma unroll
      for (int mt = 0; mt < MT; ++mt)
#pragma unroll
        for (int nt = 0; nt < NT; ++nt)
          acc[mt][nt] = __builtin_amdgcn_mfma_f32_16x16x32_bf16(
              af[s][mt], bfr[s][nt], acc[mt][nt], 0, 0, 0);

    asm volatile("s_waitcnt lgkmcnt(0)" ::: "memory");  // this wave's reads done
    __builtin_amdgcn_sched_barrier(0);
    __builtin_amdgcn_s_barrier();            // buf pb free for overwrite
    __builtin_amdgcn_sched_barrier(0);       // stage not hoisted above barrier

    if (kt + NBUF < KT) stage(kt + NBUF, pb);
    pb = (pb + 1 == NBUF) ? 0 : pb + 1;
  }

  const int ng0 = bn * BN + wn + mlane;
  const int mg0 = bm * BM + wm + quad * 4;

  if (EPI == 0) {
    float bv[NT];
#pragma unroll
    for (int nt = 0; nt < NT; ++nt) {
      int n = ng0 + nt * 16;
      bv[nt] = (n < bias_n) ? bias[n] : 0.f;
    }
#pragma unroll
    for (int mt = 0; mt < MT; ++mt)
#pragma unroll
      for (int nt = 0; nt < NT; ++nt)
#pragma unroll
        for (int r = 0; r < 4; ++r) {
          int m = mg0 + mt * 16 + r;
          int n = ng0 + nt * 16;
          float v = fmaxf(acc[mt][nt][r] + bv[nt], 0.f);
          C[(size_t)m * NPAD + n] = (bf16)v;
        }
  } else {
    const float2* x2 = (const float2*)x;
    float2* y2 = (float2*)y;
#pragma unroll
    for (int nt = 0; nt < NT; ++nt) {
      int n = ng0 + nt * 16;
      if (n < HALF) {
        float bb = bias[n];
#pragma unroll
        for (int mt = 0; mt < MT; ++mt)
#pragma unroll
          for (int r = 0; r < 4; ++r) {
            int m = mg0 + mt * 16 + r;
            size_t off = (size_t)m * (D_IN / 2) + n;
            float2 v = x2[off];
            v.y += acc[mt][nt][r] + bb;
            y2[off] = v;
          }
      }
    }
  }
}

extern "C" void kernel_launch(void* const* d_in, const int* in_sizes, int n_in,
                              void* d_out, int out_size, void* d_ws, size_t ws_size,
                              hipStream_t stream) {
  const float* x     = (const float*)d_in[0];
  const float* ldj   = (const float*)d_in[1];
  const float* W_in  = (const float*)d_in[2];
  const float* b_in  = (const float*)d_in[3];
  const float* W_hid = (const float*)d_in[4];
  const float* b_hid = (const float*)d_in[5];
  const float* W_out = (const float*)d_in[6];
  const float* b_out = (const float*)d_in[7];
  float* y = (float*)d_out;

  // workspace layout (bytes, 256-aligned)
  char* p = (char*)d_ws;
  bf16* A0  = (bf16*)(p + 0);           // 4096 x 448   (3,670,016 B)
  bf16* H0  = (bf16*)(p + 3670016);     // 4096 x 1024  (8,388,608 B)
  bf16* H1  = (bf16*)(p + 12058624);    // 4096 x 1024
  bf16* WT0 = (bf16*)(p + 20447232);    // 1024 x 448   (917,504 B)
  bf16* WTh = (bf16*)(p + 21364736);    // 4 x 1024 x 1024 (8,388,608 B)
  bf16* WT5 = (bf16*)(p + 29753344);    // 512 x 1024   (1,048,576 B)

  const size_t WH = (size_t)NPAD * NPAD;

  // --- prep: pack + ALL transposes + ldj (1 dispatch, high-occupancy) ---
  prep_k<<<dim3(896 + 5056), 256, 0, stream>>>(x, ldj, W_in, W_hid, W_out,
                                               A0, WT0, WTh, WT5, y);

  // --- MLP: 6 GEMMs. Hidden: 128x128 tiles (64x64/wave), 256 blocks, 3-buf. ---
  gemm_k<128, 128, 0, K0PAD><<<dim3(256), 256, 0, stream>>>(
      A0, WT0, b_in, MID, H0, nullptr, nullptr);
  gemm_k<128, 128, 0, NPAD><<<dim3(256), 256, 0, stream>>>(
      H0, WTh + 0 * WH, b_hid + 0 * MID, MID, H1, nullptr, nullptr);
  gemm_k<128, 128, 0, NPAD><<<dim3(256), 256, 0, stream>>>(
      H1, WTh + 1 * WH, b_hid + 1 * MID, MID, H0, nullptr, nullptr);
  gemm_k<128, 128, 0, NPAD><<<dim3(256), 256, 0, stream>>>(
      H0, WTh + 2 * WH, b_hid + 2 * MID, MID, H1, nullptr, nullptr);
  gemm_k<128, 128, 0, NPAD><<<dim3(256), 256, 0, stream>>>(
      H1, WTh + 3 * WH, b_hid + 3 * MID, MID, H0, nullptr, nullptr);
  // final: 128x64 tiles over N=512 -> 32 x 8 = 256 blocks; writes BOTH y columns
  gemm_k<128, 64, 1, NPAD><<<dim3(256), 256, 0, stream>>>(
      H0, WT5, b_out, HALF, nullptr, x, y);
}